// Round 3
// baseline (1257.887 us; speedup 1.0000x reference)
//
#include <hip/hip_runtime.h>

// ParallelExpert: grouped SwiGLU MLP, E=8 experts.
//   h = x @ w1          x:[E,T,DIN] f32, w1:[E,DIN,2*DHID] f32
//   h_act = silu(h[:, :DHID]) * h[:, DHID:]
//   out = h_act @ w2    w2:[E,DHID,DOUT] f32 -> out:[E,T,DOUT] f32
// Strategy: convert/transpose weights to f16 (B^T layout) in ws, f16 MFMA
// (16x16x32) with fp32 accumulate. f16 chosen over bf16 for the extra
// mantissa bits (inputs are fp32; threshold is tight).
// ws layout: [0,128MB) h_act f16 [E][T][DHID]; [128MB,256MB) w1t/w2t (reused).

#define E_    8
#define T_    2048
#define DIN   1024
#define DHID  4096
#define DOUT  1024
#define INTER 8192

typedef _Float16 f16x8 __attribute__((ext_vector_type(8)));
typedef float    f32x4 __attribute__((ext_vector_type(4)));

// ---- transpose + convert: src f32 [E][R][C] -> dst f16 [E][C][R] ----------
__global__ __launch_bounds__(256) void xpose_f32_f16(
    const float* __restrict__ src, _Float16* __restrict__ dst,
    int R, int C, int tR, int tC) {
  __shared__ _Float16 tile[32][33];
  int bid = blockIdx.x;
  int perE = tR * tC;
  int e = bid / perE;
  int rem = bid - e * perE;
  int rt = rem / tC;
  int ct = rem - rt * tC;
  int r0 = rt * 32, c0 = ct * 32;
  int t = threadIdx.x;
  int lr = t >> 5, lc = t & 31;
  const float* s = src + (size_t)e * R * C;
  _Float16* d = dst + (size_t)e * C * R;
#pragma unroll
  for (int i = 0; i < 4; ++i) {
    int r = lr + 8 * i;
    tile[r][lc] = (_Float16)s[(size_t)(r0 + r) * C + (c0 + lc)];
  }
  __syncthreads();
#pragma unroll
  for (int i = 0; i < 4; ++i) {
    int r = lr + 8 * i;
    d[(size_t)(c0 + r) * R + (r0 + lc)] = tile[lc][r];
  }
}

// ---- GEMM1 + SwiGLU: h_act = swiglu(x @ w1) -------------------------------
// x:[E][T][DIN] f32, w1t:[E][INTER][DIN] f16, hact:[E][T][DHID] f16
// 128x128 output tile per block (gate AND val accumulated together).
__global__ __launch_bounds__(256) void gemm1_swiglu(
    const float* __restrict__ x,
    const _Float16* __restrict__ w1t,
    _Float16* __restrict__ hact) {
  __shared__ _Float16 As[128][40];
  __shared__ _Float16 Bg[128][40];
  __shared__ _Float16 Bv[128][40];

  int bid = blockIdx.x;
  int e   = bid >> 9;          // 16*32 = 512 blocks/expert
  int rem = bid & 511;
  int mt  = rem >> 5;          // 0..15
  int nt  = rem & 31;          // 0..31
  int m0 = mt * 128, n0 = nt * 128;

  const float*    xe = x   + ((size_t)e * T_ + m0) * DIN;
  const _Float16* wg = w1t + ((size_t)e * INTER + n0) * DIN;
  const _Float16* wv = w1t + ((size_t)e * INTER + DHID + n0) * DIN;

  int tid  = threadIdx.x;
  int srow = tid >> 1;            // staging row 0..127
  int skh  = (tid & 1) * 16;      // staging k-half offset (in elems)

  int lane = tid & 63;
  int wid  = tid >> 6;
  int wr   = (wid >> 1) * 64;
  int wc   = (wid & 1) * 64;
  int lr   = lane & 15;
  int lk   = (lane >> 4) * 8;

  f32x4 accG[4][4];
  f32x4 accV[4][4];
#pragma unroll
  for (int m = 0; m < 4; ++m)
#pragma unroll
    for (int n = 0; n < 4; ++n) {
      accG[m][n] = f32x4{0.f, 0.f, 0.f, 0.f};
      accV[m][n] = f32x4{0.f, 0.f, 0.f, 0.f};
    }

  for (int k = 0; k < DIN; k += 32) {
    __syncthreads();
    // stage A (f32 -> f16 in regs)
    {
      const float* sa = xe + (size_t)srow * DIN + k + skh;
      float4 a0 = ((const float4*)sa)[0];
      float4 a1 = ((const float4*)sa)[1];
      float4 a2 = ((const float4*)sa)[2];
      float4 a3 = ((const float4*)sa)[3];
      f16x8 v0, v1;
      v0[0] = (_Float16)a0.x; v0[1] = (_Float16)a0.y;
      v0[2] = (_Float16)a0.z; v0[3] = (_Float16)a0.w;
      v0[4] = (_Float16)a1.x; v0[5] = (_Float16)a1.y;
      v0[6] = (_Float16)a1.z; v0[7] = (_Float16)a1.w;
      v1[0] = (_Float16)a2.x; v1[1] = (_Float16)a2.y;
      v1[2] = (_Float16)a2.z; v1[3] = (_Float16)a2.w;
      v1[4] = (_Float16)a3.x; v1[5] = (_Float16)a3.y;
      v1[6] = (_Float16)a3.z; v1[7] = (_Float16)a3.w;
      *(f16x8*)&As[srow][skh]     = v0;
      *(f16x8*)&As[srow][skh + 8] = v1;
    }
    // stage Bg / Bv (already f16, 2x16B each)
    {
      const f16x8* sg = (const f16x8*)(wg + (size_t)srow * DIN + k + skh);
      *(f16x8*)&Bg[srow][skh]     = sg[0];
      *(f16x8*)&Bg[srow][skh + 8] = sg[1];
      const f16x8* sv = (const f16x8*)(wv + (size_t)srow * DIN + k + skh);
      *(f16x8*)&Bv[srow][skh]     = sv[0];
      *(f16x8*)&Bv[srow][skh + 8] = sv[1];
    }
    __syncthreads();

    f16x8 af[4], bg[4], bv[4];
#pragma unroll
    for (int m = 0; m < 4; ++m)
      af[m] = *(const f16x8*)&As[wr + m * 16 + lr][lk];
#pragma unroll
    for (int n = 0; n < 4; ++n) {
      bg[n] = *(const f16x8*)&Bg[wc + n * 16 + lr][lk];
      bv[n] = *(const f16x8*)&Bv[wc + n * 16 + lr][lk];
    }
#pragma unroll
    for (int m = 0; m < 4; ++m)
#pragma unroll
      for (int n = 0; n < 4; ++n) {
        accG[m][n] = __builtin_amdgcn_mfma_f32_16x16x32_f16(af[m], bg[n], accG[m][n], 0, 0, 0);
        accV[m][n] = __builtin_amdgcn_mfma_f32_16x16x32_f16(af[m], bv[n], accV[m][n], 0, 0, 0);
      }
  }

  // epilogue: SwiGLU in fp32, store f16
  // C/D layout (16x16): col = lane&15, row = (lane>>4)*4 + reg
  _Float16* he = hact + (size_t)e * T_ * DHID;
  int rbase = m0 + wr + (lane >> 4) * 4;
  int cbase = n0 + wc + lr;
#pragma unroll
  for (int m = 0; m < 4; ++m)
#pragma unroll
    for (int n = 0; n < 4; ++n)
#pragma unroll
      for (int j = 0; j < 4; ++j) {
        int row = rbase + m * 16 + j;
        int col = cbase + n * 16;
        float g = accG[m][n][j];
        float v = accV[m][n][j];
        float s = g / (1.0f + __expf(-g));   // silu(g)
        he[(size_t)row * DHID + col] = (_Float16)(s * v);
      }
}

// ---- GEMM2: out = h_act @ w2 ----------------------------------------------
// hact:[E][T][DHID] f16, w2t:[E][DOUT][DHID] f16, out:[E][T][DOUT] f32
__global__ __launch_bounds__(256) void gemm2(
    const _Float16* __restrict__ hact,
    const _Float16* __restrict__ w2t,
    float* __restrict__ out) {
  __shared__ _Float16 As[128][40];
  __shared__ _Float16 Bs[128][40];

  int bid = blockIdx.x;
  int e   = bid >> 7;          // 16*8 = 128 blocks/expert
  int rem = bid & 127;
  int mt  = rem >> 3;          // 0..15
  int nt  = rem & 7;           // 0..7
  int m0 = mt * 128, n0 = nt * 128;

  const _Float16* ha = hact + ((size_t)e * T_ + m0) * DHID;
  const _Float16* wb = w2t  + ((size_t)e * DOUT + n0) * DHID;

  int tid  = threadIdx.x;
  int srow = tid >> 1;
  int skh  = (tid & 1) * 16;

  int lane = tid & 63;
  int wid  = tid >> 6;
  int wr   = (wid >> 1) * 64;
  int wc   = (wid & 1) * 64;
  int lr   = lane & 15;
  int lk   = (lane >> 4) * 8;

  f32x4 acc[4][4];
#pragma unroll
  for (int m = 0; m < 4; ++m)
#pragma unroll
    for (int n = 0; n < 4; ++n) acc[m][n] = f32x4{0.f, 0.f, 0.f, 0.f};

  for (int k = 0; k < DHID; k += 32) {
    __syncthreads();
    {
      const f16x8* sa = (const f16x8*)(ha + (size_t)srow * DHID + k + skh);
      *(f16x8*)&As[srow][skh]     = sa[0];
      *(f16x8*)&As[srow][skh + 8] = sa[1];
      const f16x8* sb = (const f16x8*)(wb + (size_t)srow * DHID + k + skh);
      *(f16x8*)&Bs[srow][skh]     = sb[0];
      *(f16x8*)&Bs[srow][skh + 8] = sb[1];
    }
    __syncthreads();

    f16x8 af[4], bf[4];
#pragma unroll
    for (int m = 0; m < 4; ++m)
      af[m] = *(const f16x8*)&As[wr + m * 16 + lr][lk];
#pragma unroll
    for (int n = 0; n < 4; ++n)
      bf[n] = *(const f16x8*)&Bs[wc + n * 16 + lr][lk];
#pragma unroll
    for (int m = 0; m < 4; ++m)
#pragma unroll
      for (int n = 0; n < 4; ++n)
        acc[m][n] = __builtin_amdgcn_mfma_f32_16x16x32_f16(af[m], bf[n], acc[m][n], 0, 0, 0);
  }

  float* oe = out + (size_t)e * T_ * DOUT;
  int rbase = m0 + wr + (lane >> 4) * 4;
  int cbase = n0 + wc + lr;
#pragma unroll
  for (int m = 0; m < 4; ++m)
#pragma unroll
    for (int n = 0; n < 4; ++n)
#pragma unroll
      for (int j = 0; j < 4; ++j) {
        int row = rbase + m * 16 + j;
        int col = cbase + n * 16;
        oe[(size_t)row * DOUT + col] = acc[m][n][j];
      }
}

extern "C" void kernel_launch(void* const* d_in, const int* in_sizes, int n_in,
                              void* d_out, int out_size, void* d_ws, size_t ws_size,
                              hipStream_t stream) {
  const float* x  = (const float*)d_in[0];   // [E][T][DIN]
  const float* w1 = (const float*)d_in[1];   // [E][DIN][INTER]
  const float* w2 = (const float*)d_in[2];   // [E][DHID][DOUT]
  float* out = (float*)d_out;                // [E][T][DOUT]

  _Float16* hact = (_Float16*)d_ws;                                  // 128 MB
  _Float16* wt   = (_Float16*)((char*)d_ws + (size_t)E_ * T_ * DHID * 2); // 128 MB

  // 1) w1 [E][DIN][INTER] -> w1t [E][INTER][DIN] (f16)
  xpose_f32_f16<<<E_ * (DIN / 32) * (INTER / 32), 256, 0, stream>>>(
      w1, wt, DIN, INTER, DIN / 32, INTER / 32);
  // 2) fused GEMM1 + SwiGLU
  gemm1_swiglu<<<E_ * 16 * 32, 256, 0, stream>>>(x, wt, hact);
  // 3) w2 [E][DHID][DOUT] -> w2t [E][DOUT][DHID] (f16), reusing wt region
  xpose_f32_f16<<<E_ * (DHID / 32) * (DOUT / 32), 256, 0, stream>>>(
      w2, wt, DHID, DOUT, DHID / 32, DOUT / 32);
  // 4) GEMM2
  gemm2<<<E_ * 16 * 8, 256, 0, stream>>>(hact, wt, out);
}

// Round 4
// 744.703 us; speedup vs baseline: 1.6891x; 1.6891x over previous
//
#include <hip/hip_runtime.h>

// ParallelExpert: grouped SwiGLU MLP, E=8 experts.
//   h = x @ w1 ; h_act = silu(gate)*val ; out = h_act @ w2
// f16 MFMA (16x16x32) with fp32 accumulate.
// Round 4: global_load_lds staging for f16 tiles; gemm1 -> 8 waves with
// 64-reg dual accumulator (was 128-reg -> 1 wave/SIMD occupancy collapse).
// ws layout: [0,128MB) h_act f16 [E][T][DHID]; [128MB,256MB) w1t/w2t (reused).

#define E_    8
#define T_    2048
#define DIN   1024
#define DHID  4096
#define DOUT  1024
#define INTER 8192

typedef _Float16 f16;
typedef _Float16 f16x8 __attribute__((ext_vector_type(8)));
typedef float    f32x4 __attribute__((ext_vector_type(4)));

typedef const __attribute__((address_space(1))) void gvoid_t;
typedef __attribute__((address_space(3))) void lvoid_t;

// async global->LDS, 16B per lane; lds dest = wave-uniform base + lane*16
__device__ __forceinline__ void gload_lds16(const void* g, void* l) {
  __builtin_amdgcn_global_load_lds((gvoid_t*)g, (lvoid_t*)l, 16, 0, 0);
}

// ---- transpose + convert: src f32 [E][R][C] -> dst f16 [E][C][R] ----------
__global__ __launch_bounds__(256) void xpose_f32_f16(
    const float* __restrict__ src, f16* __restrict__ dst,
    int R, int C, int tR, int tC) {
  __shared__ f16 tile[32][33];
  int bid = blockIdx.x;
  int perE = tR * tC;
  int e = bid / perE;
  int rem = bid - e * perE;
  int rt = rem / tC;
  int ct = rem - rt * tC;
  int r0 = rt * 32, c0 = ct * 32;
  int t = threadIdx.x;
  int lr = t >> 5, lc = t & 31;
  const float* s = src + (size_t)e * R * C;
  f16* d = dst + (size_t)e * C * R;
#pragma unroll
  for (int i = 0; i < 4; ++i) {
    int r = lr + 8 * i;
    tile[r][lc] = (f16)s[(size_t)(r0 + r) * C + (c0 + lc)];
  }
  __syncthreads();
#pragma unroll
  for (int i = 0; i < 4; ++i) {
    int r = lr + 8 * i;
    d[(size_t)(c0 + r) * R + (r0 + lc)] = tile[lc][r];
  }
}

// ---- GEMM1 + SwiGLU -------------------------------------------------------
// x:[E][T][DIN] f32, w1t:[E][INTER][DIN] f16, hact:[E][T][DHID] f16
// 512 threads = 8 waves (2M x 4N); block tile 128x128; per-wave 64x32 dual.
__global__ __launch_bounds__(512, 2) void gemm1_swiglu(
    const float* __restrict__ x,
    const f16* __restrict__ w1t,
    f16* __restrict__ hact) {
  __shared__ f16 As[128][36];   // reg-staged (fp32 source), padded
  __shared__ f16 Bg[128][32];   // global_load_lds (linear, no padding!)
  __shared__ f16 Bv[128][32];

  int bid = blockIdx.x;
  int e   = bid >> 9;          // 16*32 = 512 blocks/expert
  int rem = bid & 511;
  int mt  = rem >> 5;
  int nt  = rem & 31;
  int m0 = mt * 128, n0 = nt * 128;

  const float* xe = x   + ((size_t)e * T_ + m0) * DIN;
  const f16*   wg = w1t + ((size_t)e * INTER + n0) * DIN;
  const f16*   wv = w1t + ((size_t)e * INTER + DHID + n0) * DIN;

  int tid  = threadIdx.x;
  int lane = tid & 63;
  int wid  = tid >> 6;           // 0..7

  // A staging: thread -> row tid>>2 (0..127), col (tid&3)*8
  int arow = tid >> 2;
  int acol = (tid & 3) * 8;
  // B staging via gload_lds: wave wid covers rows wid*16 .. wid*16+15
  int brow = wid * 16 + (lane >> 2);
  int bcol = (lane & 3) * 8;
  f16* lG = &Bg[wid * 16][0];    // wave-uniform LDS base
  f16* lV = &Bv[wid * 16][0];

  int wm = wid >> 2;             // 0..1
  int wn = wid & 3;              // 0..3
  int lr = lane & 15;
  int lk = (lane >> 4) * 8;

  f32x4 accG[4][2], accV[4][2];
#pragma unroll
  for (int m = 0; m < 4; ++m)
#pragma unroll
    for (int n = 0; n < 2; ++n) {
      accG[m][n] = f32x4{0.f, 0.f, 0.f, 0.f};
      accV[m][n] = f32x4{0.f, 0.f, 0.f, 0.f};
    }

  for (int k = 0; k < DIN; k += 32) {
    __syncthreads();   // previous compute done; safe to overwrite tiles
    // B: async global->LDS (f16, 16B/lane)
    gload_lds16(wg + (size_t)brow * DIN + k + bcol, lG);
    gload_lds16(wv + (size_t)brow * DIN + k + bcol, lV);
    // A: reg-stage fp32 -> f16
    {
      const float* sa = xe + (size_t)arow * DIN + k + acol;
      float4 a0 = ((const float4*)sa)[0];
      float4 a1 = ((const float4*)sa)[1];
      f16x8 v;
      v[0] = (f16)a0.x; v[1] = (f16)a0.y; v[2] = (f16)a0.z; v[3] = (f16)a0.w;
      v[4] = (f16)a1.x; v[5] = (f16)a1.y; v[6] = (f16)a1.z; v[7] = (f16)a1.w;
      *(f16x8*)&As[arow][acol] = v;
    }
    __syncthreads();   // compiler drains vmcnt+lgkmcnt here -> tiles ready

    f16x8 af[4], bg[2], bv[2];
#pragma unroll
    for (int m = 0; m < 4; ++m)
      af[m] = *(const f16x8*)&As[wm * 64 + m * 16 + lr][lk];
#pragma unroll
    for (int n = 0; n < 2; ++n) {
      bg[n] = *(const f16x8*)&Bg[wn * 32 + n * 16 + lr][lk];
      bv[n] = *(const f16x8*)&Bv[wn * 32 + n * 16 + lr][lk];
    }
#pragma unroll
    for (int m = 0; m < 4; ++m)
#pragma unroll
      for (int n = 0; n < 2; ++n) {
        accG[m][n] = __builtin_amdgcn_mfma_f32_16x16x32_f16(af[m], bg[n], accG[m][n], 0, 0, 0);
        accV[m][n] = __builtin_amdgcn_mfma_f32_16x16x32_f16(af[m], bv[n], accV[m][n], 0, 0, 0);
      }
  }

  // epilogue: SwiGLU in fp32, store f16
  // C/D layout (16x16): col = lane&15, row = (lane>>4)*4 + reg
  f16* he = hact + (size_t)e * T_ * DHID;
  int rbase = m0 + wm * 64 + (lane >> 4) * 4;
  int cbase = n0 + wn * 32 + lr;
#pragma unroll
  for (int m = 0; m < 4; ++m)
#pragma unroll
    for (int n = 0; n < 2; ++n)
#pragma unroll
      for (int j = 0; j < 4; ++j) {
        int row = rbase + m * 16 + j;
        int col = cbase + n * 16;
        float g = accG[m][n][j];
        float v = accV[m][n][j];
        float s = g / (1.0f + __expf(-g));   // silu(g)
        he[(size_t)row * DHID + col] = (f16)(s * v);
      }
}

// ---- GEMM2: out = h_act @ w2 ----------------------------------------------
// hact:[E][T][DHID] f16, w2t:[E][DOUT][DHID] f16, out:[E][T][DOUT] f32
// 256 threads = 4 waves (2x2); block tile 128x128; per-wave 64x64.
__global__ __launch_bounds__(256) void gemm2(
    const f16* __restrict__ hact,
    const f16* __restrict__ w2t,
    float* __restrict__ out) {
  __shared__ f16 As[128][32];   // both tiles via global_load_lds (linear)
  __shared__ f16 Bs[128][32];

  int bid = blockIdx.x;
  int e   = bid >> 7;          // 16*8 = 128 blocks/expert
  int rem = bid & 127;
  int mt  = rem >> 3;
  int nt  = rem & 7;
  int m0 = mt * 128, n0 = nt * 128;

  const f16* ha = hact + ((size_t)e * T_ + m0) * DHID;
  const f16* wb = w2t  + ((size_t)e * DOUT + n0) * DHID;

  int tid  = threadIdx.x;
  int lane = tid & 63;
  int wid  = tid >> 6;           // 0..3

  // staging: wave wid covers rows wid*32 .. wid*32+31 (two 16-row chunks)
  int srow0 = wid * 32 + (lane >> 2);
  int srow1 = srow0 + 16;
  int scol  = (lane & 3) * 8;
  f16* lA0 = &As[wid * 32][0];
  f16* lA1 = &As[wid * 32 + 16][0];
  f16* lB0 = &Bs[wid * 32][0];
  f16* lB1 = &Bs[wid * 32 + 16][0];

  int wm = wid >> 1;
  int wn = wid & 1;
  int lr = lane & 15;
  int lk = (lane >> 4) * 8;

  f32x4 acc[4][4];
#pragma unroll
  for (int m = 0; m < 4; ++m)
#pragma unroll
    for (int n = 0; n < 4; ++n) acc[m][n] = f32x4{0.f, 0.f, 0.f, 0.f};

  for (int k = 0; k < DHID; k += 32) {
    __syncthreads();
    gload_lds16(ha + (size_t)srow0 * DHID + k + scol, lA0);
    gload_lds16(ha + (size_t)srow1 * DHID + k + scol, lA1);
    gload_lds16(wb + (size_t)srow0 * DHID + k + scol, lB0);
    gload_lds16(wb + (size_t)srow1 * DHID + k + scol, lB1);
    __syncthreads();

    f16x8 af[4], bf[4];
#pragma unroll
    for (int m = 0; m < 4; ++m)
      af[m] = *(const f16x8*)&As[wm * 64 + m * 16 + lr][lk];
#pragma unroll
    for (int n = 0; n < 4; ++n)
      bf[n] = *(const f16x8*)&Bs[wn * 64 + n * 16 + lr][lk];
#pragma unroll
    for (int m = 0; m < 4; ++m)
#pragma unroll
      for (int n = 0; n < 4; ++n)
        acc[m][n] = __builtin_amdgcn_mfma_f32_16x16x32_f16(af[m], bf[n], acc[m][n], 0, 0, 0);
  }

  float* oe = out + (size_t)e * T_ * DOUT;
  int rbase = m0 + wm * 64 + (lane >> 4) * 4;
  int cbase = n0 + wn * 64 + lr;
#pragma unroll
  for (int m = 0; m < 4; ++m)
#pragma unroll
    for (int n = 0; n < 4; ++n)
#pragma unroll
      for (int j = 0; j < 4; ++j) {
        int row = rbase + m * 16 + j;
        int col = cbase + n * 16;
        oe[(size_t)row * DOUT + col] = acc[m][n][j];
      }
}

extern "C" void kernel_launch(void* const* d_in, const int* in_sizes, int n_in,
                              void* d_out, int out_size, void* d_ws, size_t ws_size,
                              hipStream_t stream) {
  const float* x  = (const float*)d_in[0];   // [E][T][DIN]
  const float* w1 = (const float*)d_in[1];   // [E][DIN][INTER]
  const float* w2 = (const float*)d_in[2];   // [E][DHID][DOUT]
  float* out = (float*)d_out;                // [E][T][DOUT]

  f16* hact = (f16*)d_ws;                                        // 128 MB
  f16* wt   = (f16*)((char*)d_ws + (size_t)E_ * T_ * DHID * 2);  // 128 MB

  // 1) w1 [E][DIN][INTER] -> w1t [E][INTER][DIN] (f16)
  xpose_f32_f16<<<E_ * (DIN / 32) * (INTER / 32), 256, 0, stream>>>(
      w1, wt, DIN, INTER, DIN / 32, INTER / 32);
  // 2) fused GEMM1 + SwiGLU
  gemm1_swiglu<<<E_ * 16 * 32, 512, 0, stream>>>(x, wt, hact);
  // 3) w2 [E][DHID][DOUT] -> w2t [E][DOUT][DHID] (f16), reusing wt region
  xpose_f32_f16<<<E_ * (DHID / 32) * (DOUT / 32), 256, 0, stream>>>(
      w2, wt, DHID, DOUT, DHID / 32, DOUT / 32);
  // 4) GEMM2
  gemm2<<<E_ * 16 * 8, 256, 0, stream>>>(hact, wt, out);
}

// Round 6
// 685.542 us; speedup vs baseline: 1.8349x; 1.0863x over previous
//
#include <hip/hip_runtime.h>

// ParallelExpert: grouped SwiGLU MLP, E=8 experts.
//   h = x @ w1 ; h_act = silu(gate)*val ; out = h_act @ w2
// f16 MFMA (16x16x32) with fp32 accumulate.
// Round 5: pre-convert x -> f16 (xh) so gemm1 stages ALL tiles via
// global_load_lds width-16 (no inner-loop cvt / ds_write). Fallback to
// reg-staged A if ws too small for xh.
// ws layout (xh path): [0,128M) hact f16; [128M,256M) w1t/w2t; [256M,288M) xh.

#define E_    8
#define T_    2048
#define DIN   1024
#define DHID  4096
#define DOUT  1024
#define INTER 8192

typedef _Float16 f16;
typedef _Float16 f16x8 __attribute__((ext_vector_type(8)));
typedef float    f32x4 __attribute__((ext_vector_type(4)));

typedef const __attribute__((address_space(1))) void gvoid_t;
typedef __attribute__((address_space(3))) void lvoid_t;

__device__ __forceinline__ void gload_lds16(const void* g, void* l) {
  __builtin_amdgcn_global_load_lds((gvoid_t*)g, (lvoid_t*)l, 16, 0, 0);
}

// ---- x f32 -> f16 bulk convert -------------------------------------------
__global__ __launch_bounds__(256) void conv_f32_f16(
    const float* __restrict__ src, f16* __restrict__ dst, int n8) {
  int i = blockIdx.x * 256 + threadIdx.x;
  int stride = gridDim.x * 256;
  for (; i < n8; i += stride) {
    const float4* s = (const float4*)(src + (size_t)i * 8);
    float4 a0 = s[0], a1 = s[1];
    f16x8 v;
    v[0] = (f16)a0.x; v[1] = (f16)a0.y; v[2] = (f16)a0.z; v[3] = (f16)a0.w;
    v[4] = (f16)a1.x; v[5] = (f16)a1.y; v[6] = (f16)a1.z; v[7] = (f16)a1.w;
    *(f16x8*)(dst + (size_t)i * 8) = v;
  }
}

// ---- transpose + convert: src f32 [E][R][C] -> dst f16 [E][C][R] ----------
__global__ __launch_bounds__(256) void xpose_f32_f16(
    const float* __restrict__ src, f16* __restrict__ dst,
    int R, int C, int tR, int tC) {
  __shared__ f16 tile[32][33];
  int bid = blockIdx.x;
  int perE = tR * tC;
  int e = bid / perE;
  int rem = bid - e * perE;
  int rt = rem / tC;
  int ct = rem - rt * tC;
  int r0 = rt * 32, c0 = ct * 32;
  int t = threadIdx.x;
  int lr = t >> 5, lc = t & 31;
  const float* s = src + (size_t)e * R * C;
  f16* d = dst + (size_t)e * C * R;
#pragma unroll
  for (int i = 0; i < 4; ++i) {
    int r = lr + 8 * i;
    tile[r][lc] = (f16)s[(size_t)(r0 + r) * C + (c0 + lc)];
  }
  __syncthreads();
#pragma unroll
  for (int i = 0; i < 4; ++i) {
    int r = lr + 8 * i;
    d[(size_t)(c0 + r) * R + (r0 + lc)] = tile[lc][r];
  }
}

// ---- GEMM1 + SwiGLU (xh path: all tiles via global_load_lds) --------------
// xh:[E][T][DIN] f16, w1t:[E][INTER][DIN] f16, hact:[E][T][DHID] f16
// 512 threads = 8 waves (2M x 4N); block tile 128x128; per-wave 64x32 dual.
__global__ __launch_bounds__(512, 2) void gemm1_swiglu_xh(
    const f16* __restrict__ xh,
    const f16* __restrict__ w1t,
    f16* __restrict__ hact) {
  __shared__ f16 As[128][32];
  __shared__ f16 Bg[128][32];
  __shared__ f16 Bv[128][32];

  int bid = blockIdx.x;
  int e   = bid >> 9;
  int rem = bid & 511;
  int mt  = rem >> 5;
  int nt  = rem & 31;
  int m0 = mt * 128, n0 = nt * 128;

  const f16* xe = xh  + ((size_t)e * T_ + m0) * DIN;
  const f16* wg = w1t + ((size_t)e * INTER + n0) * DIN;
  const f16* wv = w1t + ((size_t)e * INTER + DHID + n0) * DIN;

  int tid  = threadIdx.x;
  int lane = tid & 63;
  int wid  = tid >> 6;           // 0..7

  // staging: wave wid covers rows wid*16 .. wid*16+15 (16 rows x 32 f16 = 1KB)
  int srow = wid * 16 + (lane >> 2);
  int scol = (lane & 3) * 8;
  f16* lA = &As[wid * 16][0];
  f16* lG = &Bg[wid * 16][0];
  f16* lV = &Bv[wid * 16][0];

  int wm = wid >> 2;             // 0..1
  int wn = wid & 3;              // 0..3
  int lr = lane & 15;
  int lk = (lane >> 4) * 8;

  f32x4 accG[4][2], accV[4][2];
#pragma unroll
  for (int m = 0; m < 4; ++m)
#pragma unroll
    for (int n = 0; n < 2; ++n) {
      accG[m][n] = f32x4{0.f, 0.f, 0.f, 0.f};
      accV[m][n] = f32x4{0.f, 0.f, 0.f, 0.f};
    }

  for (int k = 0; k < DIN; k += 32) {
    __syncthreads();
    gload_lds16(xe + (size_t)srow * DIN + k + scol, lA);
    gload_lds16(wg + (size_t)srow * DIN + k + scol, lG);
    gload_lds16(wv + (size_t)srow * DIN + k + scol, lV);
    __syncthreads();

    f16x8 af[4], bg[2], bv[2];
#pragma unroll
    for (int m = 0; m < 4; ++m)
      af[m] = *(const f16x8*)&As[wm * 64 + m * 16 + lr][lk];
#pragma unroll
    for (int n = 0; n < 2; ++n) {
      bg[n] = *(const f16x8*)&Bg[wn * 32 + n * 16 + lr][lk];
      bv[n] = *(const f16x8*)&Bv[wn * 32 + n * 16 + lr][lk];
    }
#pragma unroll
    for (int m = 0; m < 4; ++m)
#pragma unroll
      for (int n = 0; n < 2; ++n) {
        accG[m][n] = __builtin_amdgcn_mfma_f32_16x16x32_f16(af[m], bg[n], accG[m][n], 0, 0, 0);
        accV[m][n] = __builtin_amdgcn_mfma_f32_16x16x32_f16(af[m], bv[n], accV[m][n], 0, 0, 0);
      }
  }

  f16* he = hact + (size_t)e * T_ * DHID;
  int rbase = m0 + wm * 64 + (lane >> 4) * 4;
  int cbase = n0 + wn * 32 + lr;
#pragma unroll
  for (int m = 0; m < 4; ++m)
#pragma unroll
    for (int n = 0; n < 2; ++n)
#pragma unroll
      for (int j = 0; j < 4; ++j) {
        int row = rbase + m * 16 + j;
        int col = cbase + n * 16;
        float g = accG[m][n][j];
        float v = accV[m][n][j];
        float s = g / (1.0f + __expf(-g));
        he[(size_t)row * DHID + col] = (f16)(s * v);
      }
}

// ---- GEMM1 fallback (reg-staged fp32 A), used if ws too small for xh ------
__global__ __launch_bounds__(512, 2) void gemm1_swiglu_rs(
    const float* __restrict__ x,
    const f16* __restrict__ w1t,
    f16* __restrict__ hact) {
  __shared__ f16 As[128][36];
  __shared__ f16 Bg[128][32];
  __shared__ f16 Bv[128][32];

  int bid = blockIdx.x;
  int e   = bid >> 9;
  int rem = bid & 511;
  int mt  = rem >> 5;
  int nt  = rem & 31;
  int m0 = mt * 128, n0 = nt * 128;

  const float* xe = x   + ((size_t)e * T_ + m0) * DIN;
  const f16*   wg = w1t + ((size_t)e * INTER + n0) * DIN;
  const f16*   wv = w1t + ((size_t)e * INTER + DHID + n0) * DIN;

  int tid  = threadIdx.x;
  int lane = tid & 63;
  int wid  = tid >> 6;

  int arow = tid >> 2;
  int acol = (tid & 3) * 8;
  int brow = wid * 16 + (lane >> 2);
  int bcol = (lane & 3) * 8;
  f16* lG = &Bg[wid * 16][0];
  f16* lV = &Bv[wid * 16][0];

  int wm = wid >> 2;
  int wn = wid & 3;
  int lr = lane & 15;
  int lk = (lane >> 4) * 8;

  f32x4 accG[4][2], accV[4][2];
#pragma unroll
  for (int m = 0; m < 4; ++m)
#pragma unroll
    for (int n = 0; n < 2; ++n) {
      accG[m][n] = f32x4{0.f, 0.f, 0.f, 0.f};
      accV[m][n] = f32x4{0.f, 0.f, 0.f, 0.f};
    }

  for (int k = 0; k < DIN; k += 32) {
    __syncthreads();
    gload_lds16(wg + (size_t)brow * DIN + k + bcol, lG);
    gload_lds16(wv + (size_t)brow * DIN + k + bcol, lV);
    {
      const float* sa = xe + (size_t)arow * DIN + k + acol;
      float4 a0 = ((const float4*)sa)[0];
      float4 a1 = ((const float4*)sa)[1];
      f16x8 v;
      v[0] = (f16)a0.x; v[1] = (f16)a0.y; v[2] = (f16)a0.z; v[3] = (f16)a0.w;
      v[4] = (f16)a1.x; v[5] = (f16)a1.y; v[6] = (f16)a1.z; v[7] = (f16)a1.w;
      *(f16x8*)&As[arow][acol] = v;
    }
    __syncthreads();

    f16x8 af[4], bg[2], bv[2];
#pragma unroll
    for (int m = 0; m < 4; ++m)
      af[m] = *(const f16x8*)&As[wm * 64 + m * 16 + lr][lk];
#pragma unroll
    for (int n = 0; n < 2; ++n) {
      bg[n] = *(const f16x8*)&Bg[wn * 32 + n * 16 + lr][lk];
      bv[n] = *(const f16x8*)&Bv[wn * 32 + n * 16 + lr][lk];
    }
#pragma unroll
    for (int m = 0; m < 4; ++m)
#pragma unroll
      for (int n = 0; n < 2; ++n) {
        accG[m][n] = __builtin_amdgcn_mfma_f32_16x16x32_f16(af[m], bg[n], accG[m][n], 0, 0, 0);
        accV[m][n] = __builtin_amdgcn_mfma_f32_16x16x32_f16(af[m], bv[n], accV[m][n], 0, 0, 0);
      }
  }

  f16* he = hact + (size_t)e * T_ * DHID;
  int rbase = m0 + wm * 64 + (lane >> 4) * 4;
  int cbase = n0 + wn * 32 + lr;
#pragma unroll
  for (int m = 0; m < 4; ++m)
#pragma unroll
    for (int n = 0; n < 2; ++n)
#pragma unroll
      for (int j = 0; j < 4; ++j) {
        int row = rbase + m * 16 + j;
        int col = cbase + n * 16;
        float g = accG[m][n][j];
        float v = accV[m][n][j];
        float s = g / (1.0f + __expf(-g));
        he[(size_t)row * DHID + col] = (f16)(s * v);
      }
}

// ---- GEMM2: out = h_act @ w2 ----------------------------------------------
__global__ __launch_bounds__(256) void gemm2(
    const f16* __restrict__ hact,
    const f16* __restrict__ w2t,
    float* __restrict__ out) {
  __shared__ f16 As[128][32];
  __shared__ f16 Bs[128][32];

  int bid = blockIdx.x;
  int e   = bid >> 7;
  int rem = bid & 127;
  int mt  = rem >> 3;
  int nt  = rem & 7;
  int m0 = mt * 128, n0 = nt * 128;

  const f16* ha = hact + ((size_t)e * T_ + m0) * DHID;
  const f16* wb = w2t  + ((size_t)e * DOUT + n0) * DHID;

  int tid  = threadIdx.x;
  int lane = tid & 63;
  int wid  = tid >> 6;

  int srow0 = wid * 32 + (lane >> 2);
  int srow1 = srow0 + 16;
  int scol  = (lane & 3) * 8;
  f16* lA0 = &As[wid * 32][0];
  f16* lA1 = &As[wid * 32 + 16][0];
  f16* lB0 = &Bs[wid * 32][0];
  f16* lB1 = &Bs[wid * 32 + 16][0];

  int wm = wid >> 1;
  int wn = wid & 1;
  int lr = lane & 15;
  int lk = (lane >> 4) * 8;

  f32x4 acc[4][4];
#pragma unroll
  for (int m = 0; m < 4; ++m)
#pragma unroll
    for (int n = 0; n < 4; ++n) acc[m][n] = f32x4{0.f, 0.f, 0.f, 0.f};

  for (int k = 0; k < DHID; k += 32) {
    __syncthreads();
    gload_lds16(ha + (size_t)srow0 * DHID + k + scol, lA0);
    gload_lds16(ha + (size_t)srow1 * DHID + k + scol, lA1);
    gload_lds16(wb + (size_t)srow0 * DHID + k + scol, lB0);
    gload_lds16(wb + (size_t)srow1 * DHID + k + scol, lB1);
    __syncthreads();

    f16x8 af[4], bf[4];
#pragma unroll
    for (int m = 0; m < 4; ++m)
      af[m] = *(const f16x8*)&As[wm * 64 + m * 16 + lr][lk];
#pragma unroll
    for (int n = 0; n < 4; ++n)
      bf[n] = *(const f16x8*)&Bs[wn * 64 + n * 16 + lr][lk];
#pragma unroll
    for (int m = 0; m < 4; ++m)
#pragma unroll
      for (int n = 0; n < 4; ++n)
        acc[m][n] = __builtin_amdgcn_mfma_f32_16x16x32_f16(af[m], bf[n], acc[m][n], 0, 0, 0);
  }

  float* oe = out + (size_t)e * T_ * DOUT;
  int rbase = m0 + wm * 64 + (lane >> 4) * 4;
  int cbase = n0 + wn * 64 + lr;
#pragma unroll
  for (int m = 0; m < 4; ++m)
#pragma unroll
    for (int n = 0; n < 4; ++n)
#pragma unroll
      for (int j = 0; j < 4; ++j) {
        int row = rbase + m * 16 + j;
        int col = cbase + n * 16;
        oe[(size_t)row * DOUT + col] = acc[m][n][j];
      }
}

extern "C" void kernel_launch(void* const* d_in, const int* in_sizes, int n_in,
                              void* d_out, int out_size, void* d_ws, size_t ws_size,
                              hipStream_t stream) {
  const float* x  = (const float*)d_in[0];
  const float* w1 = (const float*)d_in[1];
  const float* w2 = (const float*)d_in[2];
  float* out = (float*)d_out;

  const size_t HACT_B = (size_t)E_ * T_ * DHID * 2;    // 128 MB
  const size_t WT_B   = (size_t)E_ * INTER * DIN * 2;  // 128 MB
  const size_t XH_B   = (size_t)E_ * T_ * DIN * 2;     //  32 MB

  f16* hact = (f16*)d_ws;
  f16* wt   = (f16*)((char*)d_ws + HACT_B);

  // 1) w1 [E][DIN][INTER] -> w1t [E][INTER][DIN] (f16)
  xpose_f32_f16<<<E_ * (DIN / 32) * (INTER / 32), 256, 0, stream>>>(
      w1, wt, DIN, INTER, DIN / 32, INTER / 32);

  // 2) fused GEMM1 + SwiGLU
  if (ws_size >= HACT_B + WT_B + XH_B) {
    f16* xxh = (f16*)((char*)d_ws + HACT_B + WT_B);
    conv_f32_f16<<<2048, 256, 0, stream>>>(x, xxh, E_ * T_ * DIN / 8);
    gemm1_swiglu_xh<<<E_ * 16 * 32, 512, 0, stream>>>(xxh, wt, hact);
  } else {
    gemm1_swiglu_rs<<<E_ * 16 * 32, 512, 0, stream>>>(x, wt, hact);
  }

  // 3) w2 [E][DHID][DOUT] -> w2t [E][DOUT][DHID] (f16), reusing wt region
  xpose_f32_f16<<<E_ * (DHID / 32) * (DOUT / 32), 256, 0, stream>>>(
      w2, wt, DHID, DOUT, DHID / 32, DOUT / 32);
  // 4) GEMM2
  gemm2<<<E_ * 16 * 8, 256, 0, stream>>>(hact, wt, out);
}

// Round 7
// 682.181 us; speedup vs baseline: 1.8439x; 1.0049x over previous
//
#include <hip/hip_runtime.h>

// ParallelExpert: grouped SwiGLU MLP, E=8 experts.
//   h = x @ w1 ; h_act = silu(gate)*val ; out = h_act @ w2
// Round 7: gemm1 -> 256x(128g+128v) 8-phase schedule (T2+T3+T4+T5):
//   BK=64, 8 waves (2Mx4N), 128KiB LDS 2-deep dbuf, XOR swizzle
//   (byte ^= (row&7)<<4) via pre-swizzled gload_lds source + swizzled
//   ds_read, counted vmcnt(6) at phases 4/8 only, setprio around MFMA,
//   XCD-bijective block swizzle. gemm2/xpose/conv unchanged.
// ws layout: [0,128M) hact f16; [128M,256M) w1t/w2t; [256M,288M) xh.

#define E_    8
#define T_    2048
#define DIN   1024
#define DHID  4096
#define DOUT  1024
#define INTER 8192

typedef _Float16 f16;
typedef _Float16 f16x8 __attribute__((ext_vector_type(8)));
typedef float    f32x4 __attribute__((ext_vector_type(4)));

typedef const __attribute__((address_space(1))) void gvoid_t;
typedef __attribute__((address_space(3))) void lvoid_t;

__device__ __forceinline__ void gload_lds16(const void* g, void* l) {
  __builtin_amdgcn_global_load_lds((gvoid_t*)g, (lvoid_t*)l, 16, 0, 0);
}

// ---- x f32 -> f16 bulk convert -------------------------------------------
__global__ __launch_bounds__(256) void conv_f32_f16(
    const float* __restrict__ src, f16* __restrict__ dst, int n8) {
  int i = blockIdx.x * 256 + threadIdx.x;
  int stride = gridDim.x * 256;
  for (; i < n8; i += stride) {
    const float4* s = (const float4*)(src + (size_t)i * 8);
    float4 a0 = s[0], a1 = s[1];
    f16x8 v;
    v[0] = (f16)a0.x; v[1] = (f16)a0.y; v[2] = (f16)a0.z; v[3] = (f16)a0.w;
    v[4] = (f16)a1.x; v[5] = (f16)a1.y; v[6] = (f16)a1.z; v[7] = (f16)a1.w;
    *(f16x8*)(dst + (size_t)i * 8) = v;
  }
}

// ---- transpose + convert: src f32 [E][R][C] -> dst f16 [E][C][R] ----------
__global__ __launch_bounds__(256) void xpose_f32_f16(
    const float* __restrict__ src, f16* __restrict__ dst,
    int R, int C, int tR, int tC) {
  __shared__ f16 tile[32][33];
  int bid = blockIdx.x;
  int perE = tR * tC;
  int e = bid / perE;
  int rem = bid - e * perE;
  int rt = rem / tC;
  int ct = rem - rt * tC;
  int r0 = rt * 32, c0 = ct * 32;
  int t = threadIdx.x;
  int lr = t >> 5, lc = t & 31;
  const float* s = src + (size_t)e * R * C;
  f16* d = dst + (size_t)e * C * R;
#pragma unroll
  for (int i = 0; i < 4; ++i) {
    int r = lr + 8 * i;
    tile[r][lc] = (f16)s[(size_t)(r0 + r) * C + (c0 + lc)];
  }
  __syncthreads();
#pragma unroll
  for (int i = 0; i < 4; ++i) {
    int r = lr + 8 * i;
    d[(size_t)(c0 + r) * R + (r0 + lc)] = tile[lc][r];
  }
}

// ---- GEMM1 + SwiGLU, 8-phase 256x(128+128) ---------------------------------
// xh:[E][T][DIN] f16, w1t:[E][INTER][DIN] f16, hact:[E][T][DHID] f16
__global__ __launch_bounds__(512, 2) void gemm1_swiglu_8ph(
    const f16* __restrict__ xh,
    const f16* __restrict__ w1t,
    f16* __restrict__ hact) {
  // 2-deep double buffer; rows are 64 f16 = 128 B (8 x 16B quads).
  __shared__ __align__(1024) f16 As [2][256][64];  // 64 KiB
  __shared__ __align__(1024) f16 Bgs[2][128][64];  // 32 KiB
  __shared__ __align__(1024) f16 Bvs[2][128][64];  // 32 KiB

  int bid0 = blockIdx.x;
  int bid  = (bid0 & 7) * 256 + (bid0 >> 3);  // XCD swizzle (2048 % 8 == 0)
  int e   = bid >> 8;
  int rem = bid & 255;
  int mt  = rem >> 5;          // 0..7  (M tiles of 256)
  int nt  = rem & 31;          // 0..31 (N tiles of 128 gate + 128 val)
  int m0 = mt * 256, n0 = nt * 128;

  const f16* xe = xh  + ((size_t)e * T_ + m0) * DIN;
  const f16* wg = w1t + ((size_t)e * INTER + n0) * DIN;
  const f16* wv = w1t + ((size_t)e * INTER + DHID + n0) * DIN;

  int tid  = threadIdx.x;
  int lane = tid & 63;
  int wid  = tid >> 6;         // 0..7
  int wm   = wid >> 2;         // 0..1 -> rows wm*128..+127
  int wn   = wid & 3;          // 0..3 -> cols wn*32..+31 (gate & val)
  int lr   = lane & 15;
  int l16  = lane >> 4;        // 0..3

  // staging geometry: each gload_lds writes one 1KB chunk (8 rows x 128B),
  // LDS dest linear, source column pre-swizzled (involution cq ^= row&7).
  int srow = lane >> 3;                  // row within chunk (0..7)
  int scol = ((lane & 7) ^ srow) * 8;    // f16 column (pre-swizzled)

  auto stageA = [&](int buf, int kt, int i) {
    int ci = wid + 8 * i;  // chunk 0..31
    gload_lds16(xe + (size_t)(ci * 8 + srow) * DIN + kt * 64 + scol,
                (char*)&As[buf][0][0] + ci * 1024);
  };
  auto stageG = [&](int buf, int kt, int i) {
    int ci = wid + 8 * i;  // chunk 0..15
    gload_lds16(wg + (size_t)(ci * 8 + srow) * DIN + kt * 64 + scol,
                (char*)&Bgs[buf][0][0] + ci * 1024);
  };
  auto stageV = [&](int buf, int kt, int i) {
    int ci = wid + 8 * i;
    gload_lds16(wv + (size_t)(ci * 8 + srow) * DIN + kt * 64 + scol,
                (char*)&Bvs[buf][0][0] + ci * 1024);
  };

  f32x4 accG[8][2], accV[8][2];
#pragma unroll
  for (int m = 0; m < 8; ++m)
#pragma unroll
    for (int n = 0; n < 2; ++n) {
      accG[m][n] = f32x4{0.f, 0.f, 0.f, 0.f};
      accV[m][n] = f32x4{0.f, 0.f, 0.f, 0.f};
    }

  f16x8 af[4][2], bg[2][2], bv[2][2];

// swizzled ds_read of an 8-f16 fragment: row, 16B-quad cq -> cq ^ (row&7)
#define READ_AF(b, MH)                                                       \
  _Pragma("unroll") for (int m = 0; m < 4; ++m)                              \
  _Pragma("unroll") for (int kk = 0; kk < 2; ++kk) {                         \
    int row_ = wm * 128 + (MH) * 64 + m * 16 + lr;                           \
    af[m][kk] = *(const f16x8*)((const char*)&As[b][0][0] + row_ * 128 +     \
                                (((kk * 4 + l16) ^ (lr & 7)) << 4));         \
  }
#define READ_B(ARR, DST, b)                                                  \
  _Pragma("unroll") for (int n = 0; n < 2; ++n)                              \
  _Pragma("unroll") for (int kk = 0; kk < 2; ++kk) {                         \
    int row_ = wn * 32 + n * 16 + lr;                                        \
    DST[n][kk] = *(const f16x8*)((const char*)&ARR[b][0][0] + row_ * 128 +   \
                                 (((kk * 4 + l16) ^ (lr & 7)) << 4));        \
  }
#define MFMA16(ACC, BB, MH)                                                  \
  __builtin_amdgcn_s_setprio(1);                                            \
  _Pragma("unroll") for (int m = 0; m < 4; ++m)                              \
  _Pragma("unroll") for (int n = 0; n < 2; ++n)                              \
  _Pragma("unroll") for (int kk = 0; kk < 2; ++kk)                          \
    ACC[(MH) * 4 + m][n] = __builtin_amdgcn_mfma_f32_16x16x32_f16(           \
        af[m][kk], BB[n][kk], ACC[(MH) * 4 + m][n], 0, 0, 0);                \
  __builtin_amdgcn_s_setprio(0);
#define BAR() __builtin_amdgcn_s_barrier()
#define LGKM0() asm volatile("s_waitcnt lgkmcnt(0)" ::: "memory")
#define VM6() asm volatile("s_waitcnt vmcnt(6)" ::: "memory")

  // ---- prologue: tile0 full (8 loads) + tile1 minus A-chunks 2,3 (6) ----
  stageA(0, 0, 0); stageA(0, 0, 1); stageA(0, 0, 2); stageA(0, 0, 3);
  stageG(0, 0, 0); stageG(0, 0, 1);
  stageV(0, 0, 0); stageV(0, 0, 1);
  stageA(1, 1, 0); stageA(1, 1, 1);
  stageG(1, 1, 0); stageG(1, 1, 1);
  stageV(1, 1, 0); stageV(1, 1, 1);
  VM6();   // drain tile0's 8 loads (keep newest 6 = tile1 partial)
  BAR();

  // ---- main loop: 16 K-tiles, 2 per iteration ----
  for (int it = 0; it < 8; ++it) {
    int tb = 2 * it + 1;          // buf1's current tile (finish A staging)
    int pa = (2 * it + 2) & 15;   // prefetch -> buf0
    int pb = (2 * it + 3) & 15;   // prefetch -> buf1

    // P1: buf0 mh0 x gate | finish A[1] <- tb (chunks 2,3)
    READ_AF(0, 0);
    READ_B(Bgs, bg, 0);
    stageA(1, tb, 2); stageA(1, tb, 3);
    BAR(); LGKM0();
    MFMA16(accG, bg, 0);
    BAR();

    // P2: buf0 mh0 x val | stage Bg[0] <- pa   (Bg[0] consumed in P1)
    READ_B(Bvs, bv, 0);
    stageG(0, pa, 0); stageG(0, pa, 1);
    BAR(); LGKM0();
    MFMA16(accV, bv, 0);
    BAR();

    // P3: buf0 mh1 x gate | stage Bv[0] <- pa  (Bv[0] consumed in P2)
    READ_AF(0, 1);
    stageV(0, pa, 0); stageV(0, pa, 1);
    BAR(); LGKM0();
    MFMA16(accG, bg, 1);
    BAR();

    // P4: buf0 mh1 x val | stage A[0] <- pa ch 0,1 (A[0] consumed in P3)
    stageA(0, pa, 0); stageA(0, pa, 1);
    BAR();
    MFMA16(accV, bv, 1);
    VM6();  // drain tile tb's loads (prev P8 + prologue/P1) -> buf1 ready
    BAR();

    // P5: buf1 mh0 x gate | stage A[0] <- pa ch 2,3
    READ_AF(1, 0);
    READ_B(Bgs, bg, 1);
    stageA(0, pa, 2); stageA(0, pa, 3);
    BAR(); LGKM0();
    MFMA16(accG, bg, 0);
    BAR();

    // P6: buf1 mh0 x val | stage Bg[1] <- pb   (Bg[1] consumed in P5)
    READ_B(Bvs, bv, 1);
    stageG(1, pb, 0); stageG(1, pb, 1);
    BAR(); LGKM0();
    MFMA16(accV, bv, 0);
    BAR();

    // P7: buf1 mh1 x gate | stage Bv[1] <- pb  (Bv[1] consumed in P6)
    READ_AF(1, 1);
    stageV(1, pb, 0); stageV(1, pb, 1);
    BAR(); LGKM0();
    MFMA16(accG, bg, 1);
    BAR();

    // P8: buf1 mh1 x val | stage A[1] <- pb ch 0,1 (A[1] consumed in P7)
    stageA(1, pb, 0); stageA(1, pb, 1);
    BAR();
    MFMA16(accV, bv, 1);
    VM6();  // drain tile pa's loads (P2..P5) -> buf0 ready for next P1
    BAR();
  }

#undef READ_AF
#undef READ_B
#undef MFMA16
#undef BAR
#undef LGKM0
#undef VM6

  // ---- epilogue: SwiGLU, store f16 ----
  // C/D 16x16 layout: col = lane&15, row = (lane>>4)*4 + reg
  f16* he = hact + (size_t)e * T_ * DHID;
  int rbase = m0 + wm * 128 + l16 * 4;
  int cbase = n0 + wn * 32 + lr;
#pragma unroll
  for (int m = 0; m < 8; ++m)
#pragma unroll
    for (int n = 0; n < 2; ++n)
#pragma unroll
      for (int j = 0; j < 4; ++j) {
        int row = rbase + m * 16 + j;
        int col = cbase + n * 16;
        float g = accG[m][n][j];
        float v = accV[m][n][j];
        float s = g / (1.0f + __expf(-g));
        he[(size_t)row * DHID + col] = (f16)(s * v);
      }
}

// ---- GEMM1 fallback (reg-staged fp32 A), used if ws too small for xh ------
__global__ __launch_bounds__(512, 2) void gemm1_swiglu_rs(
    const float* __restrict__ x,
    const f16* __restrict__ w1t,
    f16* __restrict__ hact) {
  __shared__ f16 As[128][36];
  __shared__ f16 Bg[128][32];
  __shared__ f16 Bv[128][32];

  int bid = blockIdx.x;
  int e   = bid >> 9;
  int rem = bid & 511;
  int mt  = rem >> 5;
  int nt  = rem & 31;
  int m0 = mt * 128, n0 = nt * 128;

  const float* xe = x   + ((size_t)e * T_ + m0) * DIN;
  const f16*   wg = w1t + ((size_t)e * INTER + n0) * DIN;
  const f16*   wv = w1t + ((size_t)e * INTER + DHID + n0) * DIN;

  int tid  = threadIdx.x;
  int lane = tid & 63;
  int wid  = tid >> 6;

  int arow = tid >> 2;
  int acol = (tid & 3) * 8;
  int brow = wid * 16 + (lane >> 2);
  int bcol = (lane & 3) * 8;
  f16* lG = &Bg[wid * 16][0];
  f16* lV = &Bv[wid * 16][0];

  int wm = wid >> 2;
  int wn = wid & 3;
  int lr = lane & 15;
  int lk = (lane >> 4) * 8;

  f32x4 accG[4][2], accV[4][2];
#pragma unroll
  for (int m = 0; m < 4; ++m)
#pragma unroll
    for (int n = 0; n < 2; ++n) {
      accG[m][n] = f32x4{0.f, 0.f, 0.f, 0.f};
      accV[m][n] = f32x4{0.f, 0.f, 0.f, 0.f};
    }

  for (int k = 0; k < DIN; k += 32) {
    __syncthreads();
    gload_lds16(wg + (size_t)brow * DIN + k + bcol, lG);
    gload_lds16(wv + (size_t)brow * DIN + k + bcol, lV);
    {
      const float* sa = xe + (size_t)arow * DIN + k + acol;
      float4 a0 = ((const float4*)sa)[0];
      float4 a1 = ((const float4*)sa)[1];
      f16x8 v;
      v[0] = (f16)a0.x; v[1] = (f16)a0.y; v[2] = (f16)a0.z; v[3] = (f16)a0.w;
      v[4] = (f16)a1.x; v[5] = (f16)a1.y; v[6] = (f16)a1.z; v[7] = (f16)a1.w;
      *(f16x8*)&As[arow][acol] = v;
    }
    __syncthreads();

    f16x8 af[4], bg[2], bv[2];
#pragma unroll
    for (int m = 0; m < 4; ++m)
      af[m] = *(const f16x8*)&As[wm * 64 + m * 16 + lr][lk];
#pragma unroll
    for (int n = 0; n < 2; ++n) {
      bg[n] = *(const f16x8*)&Bg[wn * 32 + n * 16 + lr][lk];
      bv[n] = *(const f16x8*)&Bv[wn * 32 + n * 16 + lr][lk];
    }
#pragma unroll
    for (int m = 0; m < 4; ++m)
#pragma unroll
      for (int n = 0; n < 2; ++n) {
        accG[m][n] = __builtin_amdgcn_mfma_f32_16x16x32_f16(af[m], bg[n], accG[m][n], 0, 0, 0);
        accV[m][n] = __builtin_amdgcn_mfma_f32_16x16x32_f16(af[m], bv[n], accV[m][n], 0, 0, 0);
      }
  }

  f16* he = hact + (size_t)e * T_ * DHID;
  int rbase = m0 + wm * 64 + (lane >> 4) * 4;
  int cbase = n0 + wn * 32 + lr;
#pragma unroll
  for (int m = 0; m < 4; ++m)
#pragma unroll
    for (int n = 0; n < 2; ++n)
#pragma unroll
      for (int j = 0; j < 4; ++j) {
        int row = rbase + m * 16 + j;
        int col = cbase + n * 16;
        float g = accG[m][n][j];
        float v = accV[m][n][j];
        float s = g / (1.0f + __expf(-g));
        he[(size_t)row * DHID + col] = (f16)(s * v);
      }
}

// ---- GEMM2: out = h_act @ w2 ----------------------------------------------
__global__ __launch_bounds__(256) void gemm2(
    const f16* __restrict__ hact,
    const f16* __restrict__ w2t,
    float* __restrict__ out) {
  __shared__ f16 As[128][32];
  __shared__ f16 Bs[128][32];

  int bid = blockIdx.x;
  int e   = bid >> 7;
  int rem = bid & 127;
  int mt  = rem >> 3;
  int nt  = rem & 7;
  int m0 = mt * 128, n0 = nt * 128;

  const f16* ha = hact + ((size_t)e * T_ + m0) * DHID;
  const f16* wb = w2t  + ((size_t)e * DOUT + n0) * DHID;

  int tid  = threadIdx.x;
  int lane = tid & 63;
  int wid  = tid >> 6;

  int srow0 = wid * 32 + (lane >> 2);
  int srow1 = srow0 + 16;
  int scol  = (lane & 3) * 8;
  f16* lA0 = &As[wid * 32][0];
  f16* lA1 = &As[wid * 32 + 16][0];
  f16* lB0 = &Bs[wid * 32][0];
  f16* lB1 = &Bs[wid * 32 + 16][0];

  int wm = wid >> 1;
  int wn = wid & 1;
  int lr = lane & 15;
  int lk = (lane >> 4) * 8;

  f32x4 acc[4][4];
#pragma unroll
  for (int m = 0; m < 4; ++m)
#pragma unroll
    for (int n = 0; n < 4; ++n) acc[m][n] = f32x4{0.f, 0.f, 0.f, 0.f};

  for (int k = 0; k < DHID; k += 32) {
    __syncthreads();
    gload_lds16(ha + (size_t)srow0 * DHID + k + scol, lA0);
    gload_lds16(ha + (size_t)srow1 * DHID + k + scol, lA1);
    gload_lds16(wb + (size_t)srow0 * DHID + k + scol, lB0);
    gload_lds16(wb + (size_t)srow1 * DHID + k + scol, lB1);
    __syncthreads();

    f16x8 af[4], bf[4];
#pragma unroll
    for (int m = 0; m < 4; ++m)
      af[m] = *(const f16x8*)&As[wm * 64 + m * 16 + lr][lk];
#pragma unroll
    for (int n = 0; n < 4; ++n)
      bf[n] = *(const f16x8*)&Bs[wn * 64 + n * 16 + lr][lk];
#pragma unroll
    for (int m = 0; m < 4; ++m)
#pragma unroll
      for (int n = 0; n < 4; ++n)
        acc[m][n] = __builtin_amdgcn_mfma_f32_16x16x32_f16(af[m], bf[n], acc[m][n], 0, 0, 0);
  }

  float* oe = out + (size_t)e * T_ * DOUT;
  int rbase = m0 + wm * 64 + (lane >> 4) * 4;
  int cbase = n0 + wn * 64 + lr;
#pragma unroll
  for (int m = 0; m < 4; ++m)
#pragma unroll
    for (int n = 0; n < 4; ++n)
#pragma unroll
      for (int j = 0; j < 4; ++j) {
        int row = rbase + m * 16 + j;
        int col = cbase + n * 16;
        oe[(size_t)row * DOUT + col] = acc[m][n][j];
      }
}

extern "C" void kernel_launch(void* const* d_in, const int* in_sizes, int n_in,
                              void* d_out, int out_size, void* d_ws, size_t ws_size,
                              hipStream_t stream) {
  const float* x  = (const float*)d_in[0];
  const float* w1 = (const float*)d_in[1];
  const float* w2 = (const float*)d_in[2];
  float* out = (float*)d_out;

  const size_t HACT_B = (size_t)E_ * T_ * DHID * 2;    // 128 MB
  const size_t WT_B   = (size_t)E_ * INTER * DIN * 2;  // 128 MB
  const size_t XH_B   = (size_t)E_ * T_ * DIN * 2;     //  32 MB

  f16* hact = (f16*)d_ws;
  f16* wt   = (f16*)((char*)d_ws + HACT_B);

  // 1) w1 [E][DIN][INTER] -> w1t [E][INTER][DIN] (f16)
  xpose_f32_f16<<<E_ * (DIN / 32) * (INTER / 32), 256, 0, stream>>>(
      w1, wt, DIN, INTER, DIN / 32, INTER / 32);

  // 2) fused GEMM1 + SwiGLU
  if (ws_size >= HACT_B + WT_B + XH_B) {
    f16* xxh = (f16*)((char*)d_ws + HACT_B + WT_B);
    conv_f32_f16<<<2048, 256, 0, stream>>>(x, xxh, E_ * T_ * DIN / 8);
    gemm1_swiglu_8ph<<<E_ * 8 * 32, 512, 0, stream>>>(xxh, wt, hact);
  } else {
    gemm1_swiglu_rs<<<E_ * 16 * 32, 512, 0, stream>>>(x, wt, hact);
  }

  // 3) w2 [E][DHID][DOUT] -> w2t [E][DOUT][DHID] (f16), reusing wt region
  xpose_f32_f16<<<E_ * (DHID / 32) * (DOUT / 32), 256, 0, stream>>>(
      w2, wt, DHID, DOUT, DHID / 32, DOUT / 32);
  // 4) GEMM2
  gemm2<<<E_ * 16 * 8, 256, 0, stream>>>(hact, wt, out);
}